// Round 8
// baseline (204.543 us; speedup 1.0000x reference)
//
#include <hip/hip_runtime.h>

constexpr int BB = 8, CC = 512, TT = 8192;
constexpr int NBLOCK = 512;            // co-resident: 2 blocks/CU x 256 CU
constexpr int BPB = NBLOCK / BB;       // 64 blocks per batch
constexpr int TILE = 64;               // t per tile; each block owns 2 tiles
constexpr float MOM = 0.05f, EPSV = 1e-6f;

typedef float v4f __attribute__((ext_vector_type(4)));

__device__ __forceinline__ void wave_incl_affine(float& A, float& B) {
  const int lane = threadIdx.x & 63;
  #pragma unroll
  for (int off = 1; off < 64; off <<= 1) {
    float pA = __shfl_up(A, off, 64);
    float pB = __shfl_up(B, off, 64);
    if (lane >= off) { B = fmaf(A, pB, B); A *= pA; }
  }
}

// block-wide (512 thr) exclusive affine prefix applied to y0 = 0
__device__ __forceinline__ float block_scan_prev(float A, float B,
                                                 float* wAs, float* wBs) {
  const int lane = threadIdx.x & 63, wid = threadIdx.x >> 6;
  wave_incl_affine(A, B);
  __syncthreads();
  if (lane == 63) { wAs[wid] = A; wBs[wid] = B; }
  __syncthreads();
  float cB = 0.f;
  for (int w = 0; w < wid; ++w) cB = fmaf(wAs[w], cB, wBs[w]);
  float leA = __shfl_up(A, 1, 64);
  float leB = __shfl_up(B, 1, 64);
  if (lane == 0) { leA = 1.f; leB = 0.f; }
  return fmaf(leA, cB, leB);
}

// grid barrier over a provably co-resident grid
__device__ __forceinline__ void grid_barrier(int* c, int expected) {
  __syncthreads();                       // block quiesce (drains vmcnt)
  if (threadIdx.x == 0) {
    __hip_atomic_fetch_add(c, 1, __ATOMIC_RELEASE, __HIP_MEMORY_SCOPE_AGENT);
    while (__hip_atomic_load(c, __ATOMIC_RELAXED, __HIP_MEMORY_SCOPE_AGENT) < expected)
      __builtin_amdgcn_s_sleep(2);
  }
  __syncthreads();
  __builtin_amdgcn_fence(__ATOMIC_ACQUIRE, "agent");
}

__global__ __launch_bounds__(512, 4) void k_all(
    const float* __restrict__ x, const float* __restrict__ g,
    const float* __restrict__ Wa, const float* __restrict__ Wb,
    const float* __restrict__ Wo, const float* __restrict__ Bo,
    float* __restrict__ out,
    float* __restrict__ sa, float* __restrict__ sb, float* __restrict__ sb2,
    float* __restrict__ mean, float* __restrict__ inv,
    int* __restrict__ bar) {
  __shared__ float lwa[CC], lwb[CC], lwo[CC], lbo[CC];
  __shared__ float red[3][8][TILE];
  __shared__ float xw[32];
  __shared__ float wAs[8], wBs[8];

  const int tid = threadIdx.x;
  const int lane = tid & 63;
  const int wid = tid >> 6;
  const int b = blockIdx.x >> 6;             // / BPB
  const int ta = blockIdx.x & (BPB - 1);
  const int tA0 = ta * TILE;                 // [0, 4096)
  const int tB0 = tA0 + 4096;
  const size_t bT = (size_t)b * TT;

  // lane map: t4 = t-quad within tile, csub = channel subgroup
  const int t4 = (lane & 15) << 2;
  const int csub = lane >> 4;
  const int c0 = (wid << 6) + csub;          // first channel; step 4, 16 iters
  const float* xA = x + ((size_t)(b * CC + c0)) * TT + tA0 + t4;

  // ---- softmax over C for Wa, Wb (redundant per block); stage Wo/Bo ----
  {
    float va = Wa[tid], vb = Wb[tid];
    lwo[tid] = Wo[tid];
    lbo[tid] = Bo[tid];
    float ma = va, mb = vb;
    #pragma unroll
    for (int off = 32; off > 0; off >>= 1) {
      ma = fmaxf(ma, __shfl_down(ma, off, 64));
      mb = fmaxf(mb, __shfl_down(mb, off, 64));
    }
    if (lane == 0) { xw[wid] = ma; xw[8 + wid] = mb; }
    __syncthreads();
    ma = xw[0]; mb = xw[8];
    #pragma unroll
    for (int w = 1; w < 8; ++w) { ma = fmaxf(ma, xw[w]); mb = fmaxf(mb, xw[8 + w]); }
    const float ea = expf(va - ma), eb = expf(vb - mb);
    float sA = ea, sB = eb;
    #pragma unroll
    for (int off = 32; off > 0; off >>= 1) {
      sA += __shfl_down(sA, off, 64);
      sB += __shfl_down(sB, off, 64);
    }
    if (lane == 0) { xw[16 + wid] = sA; xw[24 + wid] = sB; }
    __syncthreads();
    sA = xw[16]; sB = xw[24];
    #pragma unroll
    for (int w = 1; w < 8; ++w) { sA += xw[16 + w]; sB += xw[24 + w]; }
    lwa[tid] = ea * (1.f / sA);
    lwb[tid] = eb * (1.f / sB);
  }
  __syncthreads();

  // ---- phase 1, tile A: reduce + keep x in registers (scalar-pinned) ----
  float xs[64];
  {
    v4f aa = {0.f, 0.f, 0.f, 0.f}, ab = aa, aq = aa;
    #pragma unroll
    for (int i = 0; i < 16; ++i) {
      const int c = c0 + (i << 2);
      const v4f xv = *(const v4f*)(xA + ((size_t)(i << 2)) * TT);
      xs[4*i+0] = xv.x; xs[4*i+1] = xv.y; xs[4*i+2] = xv.z; xs[4*i+3] = xv.w;
      const float wac = lwa[c], wbc = lwb[c];
      aa += wac * xv;
      ab += wbc * xv;
      aq += (wbc * xv) * xv;
    }
    #pragma unroll
    for (int k = 0; k < 4; ++k) {
      aa[k] += __shfl_xor(aa[k], 16, 64); ab[k] += __shfl_xor(ab[k], 16, 64);
      aq[k] += __shfl_xor(aq[k], 16, 64);
      aa[k] += __shfl_xor(aa[k], 32, 64); ab[k] += __shfl_xor(ab[k], 32, 64);
      aq[k] += __shfl_xor(aq[k], 32, 64);
    }
    if (lane < 16) {
      *(v4f*)&red[0][wid][t4] = aa;
      *(v4f*)&red[1][wid][t4] = ab;
      *(v4f*)&red[2][wid][t4] = aq;
    }
  }
  // pin every element in a VGPR: loads cannot be sunk past / rematerialized
  #pragma unroll
  for (int i = 0; i < 64; ++i) asm volatile("" : "+v"(xs[i]));
  __syncthreads();
  if (wid == 0) {
    float s0 = 0.f, s1 = 0.f, s2 = 0.f;
    #pragma unroll
    for (int w = 0; w < 8; ++w) {
      s0 += red[0][w][lane]; s1 += red[1][w][lane]; s2 += red[2][w][lane];
    }
    sa[bT + tA0 + lane] = s0; sb[bT + tA0 + lane] = s1; sb2[bT + tA0 + lane] = s2;
  }
  __syncthreads();   // wave0 done reading red before tile B overwrites it

  // ---- phase 1, tile B: streaming reduce (x discarded) ----
  {
    v4f aa = {0.f, 0.f, 0.f, 0.f}, ab = aa, aq = aa;
    #pragma unroll
    for (int i = 0; i < 16; ++i) {
      const int c = c0 + (i << 2);
      const v4f xv = *(const v4f*)(xA + 4096 + ((size_t)(i << 2)) * TT);
      const float wac = lwa[c], wbc = lwb[c];
      aa += wac * xv;
      ab += wbc * xv;
      aq += (wbc * xv) * xv;
    }
    #pragma unroll
    for (int k = 0; k < 4; ++k) {
      aa[k] += __shfl_xor(aa[k], 16, 64); ab[k] += __shfl_xor(ab[k], 16, 64);
      aq[k] += __shfl_xor(aq[k], 16, 64);
      aa[k] += __shfl_xor(aa[k], 32, 64); ab[k] += __shfl_xor(ab[k], 32, 64);
      aq[k] += __shfl_xor(aq[k], 32, 64);
    }
    if (lane < 16) {
      *(v4f*)&red[0][wid][t4] = aa;
      *(v4f*)&red[1][wid][t4] = ab;
      *(v4f*)&red[2][wid][t4] = aq;
    }
  }
  __syncthreads();
  if (wid == 0) {
    float s0 = 0.f, s1 = 0.f, s2 = 0.f;
    #pragma unroll
    for (int w = 0; w < 8; ++w) {
      s0 += red[0][w][lane]; s1 += red[1][w][lane]; s2 += red[2][w][lane];
    }
    sa[bT + tB0 + lane] = s0; sb[bT + tB0 + lane] = s1; sb2[bT + tB0 + lane] = s2;
  }

  grid_barrier(&bar[0], NBLOCK);

  // ---- phase 2: blocks 0..7 scan batch = blockIdx over full T ----
  if (blockIdx.x < BB) {
    const size_t sbase = (size_t)blockIdx.x * TT + (size_t)tid * 16;
    float gt[16];
    float A = 1.f, Bv = 0.f;
    #pragma unroll
    for (int j = 0; j < 16; j += 4) {
      const v4f gq = *(const v4f*)(g  + sbase + j);
      const v4f aq = *(const v4f*)(sa + sbase + j);
      #pragma unroll
      for (int k = 0; k < 4; ++k) {
        const float gg = gq[k] * MOM;
        gt[j + k] = gg;
        const float a = 1.f - gg;
        Bv = fmaf(a, Bv, gg * aq[k]);
        A *= a;
      }
    }
    float m = block_scan_prev(A, Bv, wAs, wBs);

    float A2 = 1.f, B2 = 0.f;
    #pragma unroll
    for (int j = 0; j < 16; j += 4) {
      const v4f aq = *(const v4f*)(sa  + sbase + j);
      const v4f bq = *(const v4f*)(sb  + sbase + j);
      const v4f qq = *(const v4f*)(sb2 + sbase + j);
      v4f mq;
      #pragma unroll
      for (int k = 0; k < 4; ++k) {
        const float gg = gt[j + k], a = 1.f - gg;
        m = fmaf(a, m, gg * aq[k]);
        mq[k] = m;
        const float vi = fmaf(m, m, fmaf(-2.f * m, bq[k], qq[k]));  // sum(wb)=1
        B2 = fmaf(a, B2, gg * vi);
        A2 *= a;
      }
      *(v4f*)(mean + sbase + j) = mq;
    }
    float v = block_scan_prev(A2, B2, wAs, wBs);

    #pragma unroll
    for (int j = 0; j < 16; j += 4) {
      const v4f mq = *(const v4f*)(mean + sbase + j);
      const v4f bq = *(const v4f*)(sb   + sbase + j);
      const v4f qq = *(const v4f*)(sb2  + sbase + j);
      v4f iq;
      #pragma unroll
      for (int k = 0; k < 4; ++k) {
        const float gg = gt[j + k], a = 1.f - gg;
        const float vi = fmaf(mq[k], mq[k], fmaf(-2.f * mq[k], bq[k], qq[k]));
        v = fmaf(a, v, gg * vi);
        iq[k] = rsqrtf(v + EPSV);
      }
      *(v4f*)(inv + sbase + j) = iq;
    }
  }

  grid_barrier(&bar[16], NBLOCK);

  // ---- phase 3, tile A: normalize from registers ----
  {
    const v4f mA = *(const v4f*)(mean + bT + tA0 + t4);
    const v4f iA = *(const v4f*)(inv  + bT + tA0 + t4);
    float* oA = out + ((size_t)(b * CC + c0)) * TT + tA0 + t4;
    #pragma unroll
    for (int i = 0; i < 16; ++i) {
      const int c = c0 + (i << 2);
      v4f xv;
      xv.x = xs[4*i+0]; xv.y = xs[4*i+1]; xv.z = xs[4*i+2]; xv.w = xs[4*i+3];
      v4f o = (xv - mA) * iA * lwo[c] + lbo[c];
      __builtin_nontemporal_store(o, (v4f*)(oA + ((size_t)(i << 2)) * TT));
    }
  }
  // ---- phase 3, tile B: re-read (L3-hopeful), normalize ----
  {
    const v4f mB = *(const v4f*)(mean + bT + tB0 + t4);
    const v4f iB = *(const v4f*)(inv  + bT + tB0 + t4);
    float* oB = out + ((size_t)(b * CC + c0)) * TT + tB0 + t4;
    #pragma unroll
    for (int i = 0; i < 16; ++i) {
      const int c = c0 + (i << 2);
      const v4f xv = *(const v4f*)(xA + 4096 + ((size_t)(i << 2)) * TT);
      v4f o = (xv - mB) * iB * lwo[c] + lbo[c];
      __builtin_nontemporal_store(o, (v4f*)(oB + ((size_t)(i << 2)) * TT));
    }
  }
}

extern "C" void kernel_launch(void* const* d_in, const int* in_sizes, int n_in,
                              void* d_out, int out_size, void* d_ws, size_t ws_size,
                              hipStream_t stream) {
  const float* x  = (const float*)d_in[0];  // (B, C, T)
  const float* g  = (const float*)d_in[1];  // (B, 1, T)
  const float* Wa = (const float*)d_in[2];  // (1, C, 1)
  const float* Wb = (const float*)d_in[3];  // (1, C, 1)
  const float* Wo = (const float*)d_in[4];  // (C, 1, 1)
  const float* Bo = (const float*)d_in[5];  // (C,)
  float* out = (float*)d_out;

  constexpr int BT = BB * TT;
  int* bar    = (int*)d_ws;                 // 2 counters, 64-B spaced
  float* sa   = (float*)(bar + 32);         // BT each
  float* sb   = sa + BT;
  float* sb2  = sb + BT;
  float* mean = sb2 + BT;
  float* inv  = mean + BT;

  hipMemsetAsync(d_ws, 0, 32 * sizeof(int), stream);  // reset barrier counters
  k_all<<<NBLOCK, 512, 0, stream>>>(x, g, Wa, Wb, Wo, Bo, out,
                                    sa, sb, sb2, mean, inv, bar);
}

// Round 9
// 201.766 us; speedup vs baseline: 1.0138x; 1.0138x over previous
//
#include <hip/hip_runtime.h>

constexpr int BB = 8, CC = 512, TT = 8192;
constexpr int NBLOCK = 512;            // co-resident: 2 blocks/CU x 256 CU
constexpr int BPB = NBLOCK / BB;       // 64 blocks per batch
constexpr int TILE = 64;               // t per tile; each block owns 2 tiles
constexpr float MOM = 0.05f, EPSV = 1e-6f;

typedef float v4f __attribute__((ext_vector_type(4)));

__device__ __forceinline__ void wave_incl_affine(float& A, float& B) {
  const int lane = threadIdx.x & 63;
  #pragma unroll
  for (int off = 1; off < 64; off <<= 1) {
    float pA = __shfl_up(A, off, 64);
    float pB = __shfl_up(B, off, 64);
    if (lane >= off) { B = fmaf(A, pB, B); A *= pA; }
  }
}

// block-wide (512 thr) exclusive affine prefix applied to y0 = 0
__device__ __forceinline__ float block_scan_prev(float A, float B,
                                                 float* wAs, float* wBs) {
  const int lane = threadIdx.x & 63, wid = threadIdx.x >> 6;
  wave_incl_affine(A, B);
  __syncthreads();
  if (lane == 63) { wAs[wid] = A; wBs[wid] = B; }
  __syncthreads();
  float cB = 0.f;
  for (int w = 0; w < wid; ++w) cB = fmaf(wAs[w], cB, wBs[w]);
  float leA = __shfl_up(A, 1, 64);
  float leB = __shfl_up(B, 1, 64);
  if (lane == 0) { leA = 1.f; leB = 0.f; }
  return fmaf(leA, cB, leB);
}

// grid barrier over a provably co-resident grid
__device__ __forceinline__ void grid_barrier(int* c, int expected) {
  __syncthreads();                       // block quiesce (drains vmcnt)
  if (threadIdx.x == 0) {
    __hip_atomic_fetch_add(c, 1, __ATOMIC_RELEASE, __HIP_MEMORY_SCOPE_AGENT);
    while (__hip_atomic_load(c, __ATOMIC_RELAXED, __HIP_MEMORY_SCOPE_AGENT) < expected)
      __builtin_amdgcn_s_sleep(2);
  }
  __syncthreads();
  __builtin_amdgcn_fence(__ATOMIC_ACQUIRE, "agent");
}

__global__ __launch_bounds__(512, 4) void k_all(
    const float* __restrict__ x, const float* __restrict__ g,
    const float* __restrict__ Wa, const float* __restrict__ Wb,
    const float* __restrict__ Wo, const float* __restrict__ Bo,
    float* __restrict__ out,
    float* __restrict__ sa, float* __restrict__ sb, float* __restrict__ sb2,
    float* __restrict__ mean, float* __restrict__ inv,
    int* __restrict__ bar) {
  __shared__ float lwa[CC], lwb[CC], lwo[CC], lbo[CC];
  __shared__ float red[3][8][TILE];
  __shared__ float xw[32];
  __shared__ float wAs[8], wBs[8];

  const int tid = threadIdx.x;
  const int lane = tid & 63;
  const int wid = tid >> 6;
  const int b = blockIdx.x >> 6;             // / BPB
  const int ta = blockIdx.x & (BPB - 1);
  const int tA0 = ta * TILE;                 // [0, 4096)
  const int tB0 = tA0 + 4096;
  const size_t bT = (size_t)b * TT;

  // lane map: t4 = t-quad within tile, csub = channel subgroup
  const int t4 = (lane & 15) << 2;
  const int csub = lane >> 4;
  const int c0 = (wid << 6) + csub;          // first channel; step 4, 16 iters
  const float* xA = x + ((size_t)(b * CC + c0)) * TT + tA0 + t4;

  // ---- softmax over C for Wa, Wb (redundant per block); stage Wo/Bo ----
  {
    float va = Wa[tid], vb = Wb[tid];
    lwo[tid] = Wo[tid];
    lbo[tid] = Bo[tid];
    float ma = va, mb = vb;
    #pragma unroll
    for (int off = 32; off > 0; off >>= 1) {
      ma = fmaxf(ma, __shfl_down(ma, off, 64));
      mb = fmaxf(mb, __shfl_down(mb, off, 64));
    }
    if (lane == 0) { xw[wid] = ma; xw[8 + wid] = mb; }
    __syncthreads();
    ma = xw[0]; mb = xw[8];
    #pragma unroll
    for (int w = 1; w < 8; ++w) { ma = fmaxf(ma, xw[w]); mb = fmaxf(mb, xw[8 + w]); }
    const float ea = expf(va - ma), eb = expf(vb - mb);
    float sA = ea, sB = eb;
    #pragma unroll
    for (int off = 32; off > 0; off >>= 1) {
      sA += __shfl_down(sA, off, 64);
      sB += __shfl_down(sB, off, 64);
    }
    if (lane == 0) { xw[16 + wid] = sA; xw[24 + wid] = sB; }
    __syncthreads();
    sA = xw[16]; sB = xw[24];
    #pragma unroll
    for (int w = 1; w < 8; ++w) { sA += xw[16 + w]; sB += xw[24 + w]; }
    lwa[tid] = ea * (1.f / sA);
    lwb[tid] = eb * (1.f / sB);
  }
  __syncthreads();

  // ---- phase 1, tile A: reduce + keep x in registers (scalar-pinned) ----
  float xs[64];
  {
    v4f aa = {0.f, 0.f, 0.f, 0.f}, ab = aa, aq = aa;
    #pragma unroll
    for (int i = 0; i < 16; ++i) {
      const int c = c0 + (i << 2);
      const v4f xv = *(const v4f*)(xA + ((size_t)(i << 2)) * TT);
      xs[4*i+0] = xv.x; xs[4*i+1] = xv.y; xs[4*i+2] = xv.z; xs[4*i+3] = xv.w;
      const float wac = lwa[c], wbc = lwb[c];
      aa += wac * xv;
      ab += wbc * xv;
      aq += (wbc * xv) * xv;
    }
    #pragma unroll
    for (int k = 0; k < 4; ++k) {
      aa[k] += __shfl_xor(aa[k], 16, 64); ab[k] += __shfl_xor(ab[k], 16, 64);
      aq[k] += __shfl_xor(aq[k], 16, 64);
      aa[k] += __shfl_xor(aa[k], 32, 64); ab[k] += __shfl_xor(ab[k], 32, 64);
      aq[k] += __shfl_xor(aq[k], 32, 64);
    }
    if (lane < 16) {
      *(v4f*)&red[0][wid][t4] = aa;
      *(v4f*)&red[1][wid][t4] = ab;
      *(v4f*)&red[2][wid][t4] = aq;
    }
  }
  // pin every element in a VGPR: loads cannot be sunk past / rematerialized
  #pragma unroll
  for (int i = 0; i < 64; ++i) asm volatile("" : "+v"(xs[i]));
  __syncthreads();
  if (wid == 0) {
    float s0 = 0.f, s1 = 0.f, s2 = 0.f;
    #pragma unroll
    for (int w = 0; w < 8; ++w) {
      s0 += red[0][w][lane]; s1 += red[1][w][lane]; s2 += red[2][w][lane];
    }
    sa[bT + tA0 + lane] = s0; sb[bT + tA0 + lane] = s1; sb2[bT + tA0 + lane] = s2;
  }
  __syncthreads();   // wave0 done reading red before tile B overwrites it

  // ---- phase 1, tile B: streaming reduce (x discarded) ----
  {
    v4f aa = {0.f, 0.f, 0.f, 0.f}, ab = aa, aq = aa;
    #pragma unroll
    for (int i = 0; i < 16; ++i) {
      const int c = c0 + (i << 2);
      const v4f xv = *(const v4f*)(xA + 4096 + ((size_t)(i << 2)) * TT);
      const float wac = lwa[c], wbc = lwb[c];
      aa += wac * xv;
      ab += wbc * xv;
      aq += (wbc * xv) * xv;
    }
    #pragma unroll
    for (int k = 0; k < 4; ++k) {
      aa[k] += __shfl_xor(aa[k], 16, 64); ab[k] += __shfl_xor(ab[k], 16, 64);
      aq[k] += __shfl_xor(aq[k], 16, 64);
      aa[k] += __shfl_xor(aa[k], 32, 64); ab[k] += __shfl_xor(ab[k], 32, 64);
      aq[k] += __shfl_xor(aq[k], 32, 64);
    }
    if (lane < 16) {
      *(v4f*)&red[0][wid][t4] = aa;
      *(v4f*)&red[1][wid][t4] = ab;
      *(v4f*)&red[2][wid][t4] = aq;
    }
  }
  __syncthreads();
  if (wid == 0) {
    float s0 = 0.f, s1 = 0.f, s2 = 0.f;
    #pragma unroll
    for (int w = 0; w < 8; ++w) {
      s0 += red[0][w][lane]; s1 += red[1][w][lane]; s2 += red[2][w][lane];
    }
    sa[bT + tB0 + lane] = s0; sb[bT + tB0 + lane] = s1; sb2[bT + tB0 + lane] = s2;
  }

  grid_barrier(&bar[0], NBLOCK);

  // ---- phase 2: blocks 0..7 scan batch = blockIdx over full T ----
  if (blockIdx.x < BB) {
    const size_t sbase = (size_t)blockIdx.x * TT + (size_t)tid * 16;
    float gt[16];
    float A = 1.f, Bv = 0.f;
    #pragma unroll
    for (int j = 0; j < 16; j += 4) {
      const v4f gq = *(const v4f*)(g  + sbase + j);
      const v4f aq = *(const v4f*)(sa + sbase + j);
      #pragma unroll
      for (int k = 0; k < 4; ++k) {
        const float gg = gq[k] * MOM;
        gt[j + k] = gg;
        const float a = 1.f - gg;
        Bv = fmaf(a, Bv, gg * aq[k]);
        A *= a;
      }
    }
    float m = block_scan_prev(A, Bv, wAs, wBs);

    float A2 = 1.f, B2 = 0.f;
    #pragma unroll
    for (int j = 0; j < 16; j += 4) {
      const v4f aq = *(const v4f*)(sa  + sbase + j);
      const v4f bq = *(const v4f*)(sb  + sbase + j);
      const v4f qq = *(const v4f*)(sb2 + sbase + j);
      v4f mq;
      #pragma unroll
      for (int k = 0; k < 4; ++k) {
        const float gg = gt[j + k], a = 1.f - gg;
        m = fmaf(a, m, gg * aq[k]);
        mq[k] = m;
        const float vi = fmaf(m, m, fmaf(-2.f * m, bq[k], qq[k]));  // sum(wb)=1
        B2 = fmaf(a, B2, gg * vi);
        A2 *= a;
      }
      *(v4f*)(mean + sbase + j) = mq;
    }
    float v = block_scan_prev(A2, B2, wAs, wBs);

    #pragma unroll
    for (int j = 0; j < 16; j += 4) {
      const v4f mq = *(const v4f*)(mean + sbase + j);
      const v4f bq = *(const v4f*)(sb   + sbase + j);
      const v4f qq = *(const v4f*)(sb2  + sbase + j);
      v4f iq;
      #pragma unroll
      for (int k = 0; k < 4; ++k) {
        const float gg = gt[j + k], a = 1.f - gg;
        const float vi = fmaf(mq[k], mq[k], fmaf(-2.f * mq[k], bq[k], qq[k]));
        v = fmaf(a, v, gg * vi);
        iq[k] = rsqrtf(v + EPSV);
      }
      *(v4f*)(inv + sbase + j) = iq;
    }
  }

  grid_barrier(&bar[16], NBLOCK);

  // ---- phase 3, tile A: normalize from registers ----
  {
    const v4f mA = *(const v4f*)(mean + bT + tA0 + t4);
    const v4f iA = *(const v4f*)(inv  + bT + tA0 + t4);
    float* oA = out + ((size_t)(b * CC + c0)) * TT + tA0 + t4;
    #pragma unroll
    for (int i = 0; i < 16; ++i) {
      const int c = c0 + (i << 2);
      v4f xv;
      xv.x = xs[4*i+0]; xv.y = xs[4*i+1]; xv.z = xs[4*i+2]; xv.w = xs[4*i+3];
      v4f o = (xv - mA) * iA * lwo[c] + lbo[c];
      __builtin_nontemporal_store(o, (v4f*)(oA + ((size_t)(i << 2)) * TT));
    }
  }
  // ---- phase 3, tile B: re-read (L3-hopeful), normalize ----
  {
    const v4f mB = *(const v4f*)(mean + bT + tB0 + t4);
    const v4f iB = *(const v4f*)(inv  + bT + tB0 + t4);
    float* oB = out + ((size_t)(b * CC + c0)) * TT + tB0 + t4;
    #pragma unroll
    for (int i = 0; i < 16; ++i) {
      const int c = c0 + (i << 2);
      const v4f xv = *(const v4f*)(xA + 4096 + ((size_t)(i << 2)) * TT);
      v4f o = (xv - mB) * iB * lwo[c] + lbo[c];
      __builtin_nontemporal_store(o, (v4f*)(oB + ((size_t)(i << 2)) * TT));
    }
  }
}

extern "C" void kernel_launch(void* const* d_in, const int* in_sizes, int n_in,
                              void* d_out, int out_size, void* d_ws, size_t ws_size,
                              hipStream_t stream) {
  const float* x  = (const float*)d_in[0];  // (B, C, T)
  const float* g  = (const float*)d_in[1];  // (B, 1, T)
  const float* Wa = (const float*)d_in[2];  // (1, C, 1)
  const float* Wb = (const float*)d_in[3];  // (1, C, 1)
  const float* Wo = (const float*)d_in[4];  // (C, 1, 1)
  const float* Bo = (const float*)d_in[5];  // (C,)
  float* out = (float*)d_out;

  constexpr int BT = BB * TT;
  int* bar    = (int*)d_ws;                 // 2 counters, 64-B spaced
  float* sa   = (float*)(bar + 32);         // BT each
  float* sb   = sa + BT;
  float* sb2  = sb + BT;
  float* mean = sb2 + BT;
  float* inv  = mean + BT;

  hipMemsetAsync(d_ws, 0, 32 * sizeof(int), stream);  // reset barrier counters
  k_all<<<NBLOCK, 512, 0, stream>>>(x, g, Wa, Wb, Wo, Bo, out,
                                    sa, sb, sb2, mean, inv, bar);
}